// Round 11
// baseline (384.554 us; speedup 1.0000x reference)
//
#include <hip/hip_runtime.h>

typedef unsigned short u16;
typedef unsigned long long u64;
typedef __attribute__((ext_vector_type(8))) short bf16x8;
typedef __attribute__((ext_vector_type(4))) float f32x4;
typedef __attribute__((ext_vector_type(16))) float f32x16;
typedef __attribute__((ext_vector_type(4))) _Float16 f16x4;
typedef __attribute__((ext_vector_type(2))) __fp16 h16x2;   // cvt_pkrtz return type

#define TT 2048
#define BB 4
#define EE 768
#define HH 12
#define HD 64
#define NTOK 8192  // TT*BB
#define KVB 32
#define NTILE (TT / KVB)   // 64
// sV row stride in halfs.  MUST keep byte-stride % 8 == 0 (VST=34 regressed
// 74->208us: odd-row f16x4 LDS ops lose 8B alignment -> b64 splits).
#define VST 36

__device__ __forceinline__ u16 f2bf(float f) {
  unsigned int u = __builtin_bit_cast(unsigned int, f);
  u += 0x7fffu + ((u >> 16) & 1u);   // RNE
  return (u16)(u >> 16);
}

__device__ __forceinline__ float bf2f(u16 b) {
  unsigned int u = (unsigned int)b << 16;
  return __builtin_bit_cast(float, u);
}

__device__ __forceinline__ unsigned int pack2(u16 a, u16 b) {
  return (unsigned int)a | ((unsigned int)b << 16);
}

// HW packed fp32->bf16 RNE: lo=cvt(a), hi=cvt(b).  Same rounding as f2bf.
__device__ __forceinline__ unsigned int cvtpk2(float a, float b) {
  unsigned int r;
  asm("v_cvt_pk_bf16_f32 %0, %1, %2" : "=v"(r) : "v"(a), "v"(b));
  return r;
}

__device__ __forceinline__ unsigned int pkh2(float a, float b) {
  h16x2 t = __builtin_amdgcn_cvt_pkrtz(a, b);
  return __builtin_bit_cast(unsigned int, t);
}

// global -> LDS direct copy, 16B per lane (dest = wave-uniform base + lane*16)
#define GL2LDS(gp, lp) __builtin_amdgcn_global_load_lds( \
    (const __attribute__((address_space(1))) void*)(gp), \
    (__attribute__((address_space(3))) void*)(lp), 16, 0, 0)

// ---------------------------------------------------------------------------
// K1: fused QKV projection.  Round-11: depth-2 pipeline.  R10 counters
// (MfmaUtil 11%, VALU 10%, HBM 12%, occ 33% -> all idle) showed the vmcnt
// wait at the END-of-iter ds_write exposes ~500cy of load latency every kt
// (issue->use distance was only the MFMA block).  Now: ds_write(kt+1) at TOP
// of iter kt (regs loaded a full iter ago; barrier proves buf^1 is free),
// then issue loads for kt+2.  Issue->use distance = one full iteration.
// ---------------------------------------------------------------------------
__global__ __launch_bounds__(256, 3) void proj_qkv(
    const float* __restrict__ q_in, const float* __restrict__ k_in, const float* __restrict__ v_in,
    const float* __restrict__ ipw, const float* __restrict__ ipb,
    u16* __restrict__ qh, u16* __restrict__ kh, u16* __restrict__ vh)
{
  __shared__ u16 sA[2][128 * 40];
  __shared__ u16 sB[2][192 * 40];
  const int tid = threadIdx.x;
  const int w = tid >> 6, lane = tid & 63, l32 = lane & 31, hi = lane >> 5;
  const int wm = w & 1, wn = w >> 1;
  const int orig = blockIdx.x;
  const int wg = (orig & 7) * 96 + (orig >> 3);
  const int z = wg >> 8;
  const int rem = wg & 255;
  const int bm = rem >> 2, bn = rem & 3;

  const float* A = (z == 0) ? q_in : (z == 1) ? k_in : v_in;
  const float* W = ipw + (size_t)z * EE * EE;
  const float* bias = ipb + z * EE;

  const int srow = tid >> 3, scs = tid & 7;
  const float* ag = A + (size_t)(bm * 128 + srow) * EE + scs * 4;
  const float* wgp = W + (size_t)(bn * 192 + srow) * EE + scs * 4;

  f32x16 acc[2][3] = {};
  float4 la[4], lw[6];

  // prologue: T0 -> buf0 (direct), then T1 -> regs
#pragma unroll
  for (int i = 0; i < 4; ++i) la[i] = *(const float4*)(ag + (size_t)i * 32 * EE);
#pragma unroll
  for (int i = 0; i < 6; ++i) lw[i] = *(const float4*)(wgp + (size_t)i * 32 * EE);
#pragma unroll
  for (int i = 0; i < 4; ++i) {
    u64 pk = (u64)cvtpk2(la[i].x, la[i].y) | ((u64)cvtpk2(la[i].z, la[i].w) << 32);
    *(u64*)&sA[0][(i * 32 + srow) * 40 + scs * 4] = pk;
  }
#pragma unroll
  for (int i = 0; i < 6; ++i) {
    u64 pk = (u64)cvtpk2(lw[i].x, lw[i].y) | ((u64)cvtpk2(lw[i].z, lw[i].w) << 32);
    *(u64*)&sB[0][(i * 32 + srow) * 40 + scs * 4] = pk;
  }
#pragma unroll
  for (int i = 0; i < 4; ++i) la[i] = *(const float4*)(ag + (size_t)i * 32 * EE + 32);
#pragma unroll
  for (int i = 0; i < 6; ++i) lw[i] = *(const float4*)(wgp + (size_t)i * 32 * EE + 32);

  for (int kt = 0; kt < EE / 32; ++kt) {
    const int buf = kt & 1;
    __syncthreads();   // buf's writes (prev iter) visible; buf^1 free to write
    if (kt + 1 < EE / 32) {
      const int nb = buf ^ 1;
      // T(kt+1): regs (loads issued one full iteration ago) -> LDS
#pragma unroll
      for (int i = 0; i < 4; ++i) {
        u64 pk = (u64)cvtpk2(la[i].x, la[i].y) | ((u64)cvtpk2(la[i].z, la[i].w) << 32);
        *(u64*)&sA[nb][(i * 32 + srow) * 40 + scs * 4] = pk;
      }
#pragma unroll
      for (int i = 0; i < 6; ++i) {
        u64 pk = (u64)cvtpk2(lw[i].x, lw[i].y) | ((u64)cvtpk2(lw[i].z, lw[i].w) << 32);
        *(u64*)&sB[nb][(i * 32 + srow) * 40 + scs * 4] = pk;
      }
    }
    if (kt + 2 < EE / 32) {
      const int ko = (kt + 2) * 32;
#pragma unroll
      for (int i = 0; i < 4; ++i) la[i] = *(const float4*)(ag + (size_t)i * 32 * EE + ko);
#pragma unroll
      for (int i = 0; i < 6; ++i) lw[i] = *(const float4*)(wgp + (size_t)i * 32 * EE + ko);
    }
#pragma unroll
    for (int ks = 0; ks < 2; ++ks) {
      bf16x8 bfr[3];
#pragma unroll
      for (int tn = 0; tn < 3; ++tn)
        bfr[tn] = *(const bf16x8*)&sB[buf][(wn * 96 + tn * 32 + l32) * 40 + ks * 16 + hi * 8];
#pragma unroll
      for (int tm = 0; tm < 2; ++tm) {
        bf16x8 afr = *(const bf16x8*)&sA[buf][(wm * 64 + tm * 32 + l32) * 40 + ks * 16 + hi * 8];
#pragma unroll
        for (int tn = 0; tn < 3; ++tn)
          acc[tm][tn] = __builtin_amdgcn_mfma_f32_32x32x16_bf16(afr, bfr[tn], acc[tm][tn], 0, 0, 0);
      }
    }
  }

  const float scale = (z == 0) ? 0.125f : 1.0f;
  u16* dst = (z == 0) ? qh : (z == 1) ? kh : vh;
#pragma unroll
  for (int tn = 0; tn < 3; ++tn) {
    const int j = bn * 192 + wn * 96 + tn * 32 + l32;
    const int h = j >> 6, d = j & 63;
    const float bj = bias[j];
#pragma unroll
    for (int tm = 0; tm < 2; ++tm) {
#pragma unroll
      for (int r = 0; r < 16; ++r) {
        int m = bm * 128 + wm * 64 + tm * 32 + (r & 3) + 8 * (r >> 2) + 4 * hi;
        int t = m >> 2, bb = m & 3;
        float v = (acc[tm][tn][r] + bj) * scale;
        dst[((size_t)((bb * HH + h) * TT + t)) * HD + d] = f2bf(v);
      }
    }
  }
}

// ---------------------------------------------------------------------------
// K1b: transpose V per head:  vh bf16 [bh][t][d]  ->  vhT f16 [bh][d][t]
// ---------------------------------------------------------------------------
__global__ __launch_bounds__(256) void transpose_v(
    const u16* __restrict__ vh, _Float16* __restrict__ vhT)
{
  __shared__ u16 tile[64][72];
  const int tid = threadIdx.x;
  const int bh = blockIdx.y;
  const int t0 = blockIdx.x * 64;
  {
    int row = tid >> 2, seg = tid & 3;
    const u16* src = vh + (size_t)bh * TT * HD + (size_t)(t0 + row) * HD + seg * 16;
    uint4 a = *(const uint4*)(src);
    uint4 b = *(const uint4*)(src + 8);
    *(uint4*)&tile[row][seg * 16] = a;
    *(uint4*)&tile[row][seg * 16 + 8] = b;
  }
  __syncthreads();
  {
    int d = tid >> 2, ts = tid & 3;
    u16 tmp[16];
#pragma unroll
    for (int i = 0; i < 16; ++i) tmp[i] = tile[ts * 16 + i][d];
    unsigned int pk[8];
#pragma unroll
    for (int i = 0; i < 8; ++i)
      pk[i] = pkh2(bf2f(tmp[2 * i]), bf2f(tmp[2 * i + 1]));
    uint4 o0, o1;
    o0.x = pk[0]; o0.y = pk[1]; o0.z = pk[2]; o0.w = pk[3];
    o1.x = pk[4]; o1.y = pk[5]; o1.z = pk[6]; o1.w = pk[7];
    _Float16* dst = vhT + (size_t)bh * HD * TT + (size_t)d * TT + t0 + ts * 16;
    *(uint4*)dst = o0;
    *(uint4*)(dst + 8) = o1;
  }
}

// ---------------------------------------------------------------------------
// K2: attention — byte-exact R6 structure (proven 74us), VST=36.
// ---------------------------------------------------------------------------
__global__ __launch_bounds__(256, 3) void attn_flash(
    const u16* __restrict__ qh, const u16* __restrict__ kh, const _Float16* __restrict__ vhT,
    u16* __restrict__ ctx, float* __restrict__ stats_rl)
{
  __shared__ u16 sK[2][KVB * 64];          // [buf][row*64 + swz-chunk], 128B rows
  __shared__ _Float16 sV[2][64 * VST];     // [buf][d*VST + s], 72B rows

  const int tid = threadIdx.x, w = tid >> 6, lane = tid & 63;
  const int l16 = lane & 15, quad = lane >> 4;
  const int orig = blockIdx.x;
  const int wg = (orig & 7) * 96 + (orig >> 3);
  const int qb = wg & 15;          // 16 q-blocks of 128
  const int bhl = wg >> 4;         // 0..47
  const int b = bhl / HH, h = bhl - b * HH;
  const int q0 = qb * 128 + w * 32;
  const size_t bh = (size_t)bhl;
  const u16* qg = qh + (bh * TT + q0) * HD;
  const u16* kg = kh + bh * TT * HD;
  const _Float16* vg = vhT + bh * HD * TT;

  const int krow = tid >> 3, kch = tid & 7;            // K: 32 rows x 8 x 16B
  const int kdst = krow * 64 + ((kch ^ (krow & 7)) * 8);
  const u16* kgp = kg + (size_t)krow * HD + kch * 8;
  const int vrow = tid >> 2, vch = tid & 3;            // V: 64 rows x 4 x 16B
  const int vdst = vrow * VST + vch * 8;
  const _Float16* vgp = vg + (size_t)vrow * TT + vch * 8;

  bf16x8 qf[2][2];
#pragma unroll
  for (int j = 0; j < 2; ++j)
#pragma unroll
    for (int p = 0; p < 2; ++p)
      qf[j][p] = *(const bf16x8*)(qg + (j * 16 + l16) * HD + p * 32 + quad * 8);

  f32x4 oacc[2][4] = {};
  float lsum[2] = {0.0f, 0.0f};

  {
    uint4 kv = *(const uint4*)kgp;
    uint4 vv = *(const uint4*)vgp;
    *(uint4*)&sK[0][kdst] = kv;
    *(u64*)&sV[0][vdst]     = ((const u64*)&vv)[0];
    *(u64*)&sV[0][vdst + 4] = ((const u64*)&vv)[1];
  }

  for (int st = 0; st < NTILE; ++st) {
    const int buf = st & 1;
    uint4 nk, nv;
    const bool more = (st + 1 < NTILE);
    if (more) {        // issue before the barrier (R6-proven placement)
      nk = *(const uint4*)(kgp + (size_t)(st + 1) * KVB * HD);
      nv = *(const uint4*)(vgp + (st + 1) * KVB);
    }
    __syncthreads();

    const u16* kb = &sK[buf][0];
    const _Float16* vb = &sV[buf][0];
#pragma unroll
    for (int ss = 0; ss < 2; ++ss) {
      const int krw = ss * 16 + l16;
      bf16x8 kf0 = *(const bf16x8*)&kb[krw * 64 + ((quad ^ (krw & 7)) * 8)];
      bf16x8 kf1 = *(const bf16x8*)&kb[krw * 64 + (((4 + quad) ^ (krw & 7)) * 8)];
      f16x4 vf[4];
#pragma unroll
      for (int m = 0; m < 4; ++m)
        vf[m] = *(const f16x4*)&vb[(m * 16 + l16) * VST + ss * 16 + quad * 4];
#pragma unroll
      for (int j = 0; j < 2; ++j) {
        f32x4 z = {};
        f32x4 T = __builtin_amdgcn_mfma_f32_16x16x32_bf16(kf0, qf[j][0], z, 0, 0, 0);
        T = __builtin_amdgcn_mfma_f32_16x16x32_bf16(kf1, qf[j][1], T, 0, 0, 0);
        float p0 = __expf(T[0]), p1 = __expf(T[1]), p2 = __expf(T[2]), p3 = __expf(T[3]);
        lsum[j] += (p0 + p1) + (p2 + p3);
        uint2 uu;
        uu.x = pkh2(p0, p1);
        uu.y = pkh2(p2, p3);
        f16x4 pb = __builtin_bit_cast(f16x4, uu);
#pragma unroll
        for (int m = 0; m < 4; ++m)
          oacc[j][m] = __builtin_amdgcn_mfma_f32_16x16x16f16(vf[m], pb, oacc[j][m], 0, 0, 0);
      }
    }

    if (more) {
      const int nb = buf ^ 1;
      *(uint4*)&sK[nb][kdst] = nk;
      *(u64*)&sV[nb][vdst]     = ((const u64*)&nv)[0];
      *(u64*)&sV[nb][vdst + 4] = ((const u64*)&nv)[1];
    }
  }

#pragma unroll
  for (int j = 0; j < 2; ++j) {
    float s = lsum[j];
    s += __shfl_xor(s, 16);
    s += __shfl_xor(s, 32);
    float rl = 1.0f / s;
    const int q = q0 + j * 16 + l16;
    if (quad == 0) stats_rl[bh * TT + q] = rl;
    u16* crow = ctx + (size_t)(q * BB + b) * EE + h * HD;
#pragma unroll
    for (int m = 0; m < 4; ++m) {
      u64 pk =
          (u64)pack2(f2bf(oacc[j][m][0] * rl), f2bf(oacc[j][m][1] * rl)) |
          ((u64)pack2(f2bf(oacc[j][m][2] * rl), f2bf(oacc[j][m][3] * rl)) << 32);
      *(u64*)(crow + m * 16 + quad * 4) = pk;
    }
  }
}

// ---------------------------------------------------------------------------
// K3: avg_weights (unchanged from round 6 — gload_lds dbuf, raw barrier,
// launch_bounds(256,2)).
// ---------------------------------------------------------------------------
__global__ __launch_bounds__(256, 2) void attn_avg(
    const u16* __restrict__ qh, const u16* __restrict__ kh,
    const float* __restrict__ stats_rl, float* __restrict__ avg)
{
  __shared__ u16 sQ[2][128 * 64];
  __shared__ u16 sK[2][128 * 64];
  const int tid = threadIdx.x, w = tid >> 6, lane = tid & 63;
  const int l16 = lane & 15, quad = lane >> 4;
  const int b = blockIdx.z;
  const int q0 = blockIdx.y * 128, s0 = blockIdx.x * 128;
  const int wq = (w & 1) * 64, ws = (w >> 1) * 64;

  int goff[4], ldso[4];
#pragma unroll
  for (int i = 0; i < 4; ++i) {
    const int g = i * 256 + tid;
    const int row = g >> 3, c = g & 7;
    goff[i] = row * HD + ((c ^ (row & 7)) * 8);        // u16 units
    ldso[i] = (i * 256 + (tid & ~63)) * 8;             // wave-uniform, u16 units
  }
  const size_t bhb = (size_t)b * HH;
  const u16* qbase = qh + (bhb * TT + q0) * HD;
  const u16* kbase = kh + (bhb * TT + s0) * HD;

  f32x4 aacc[4][4] = {};

#pragma unroll
  for (int i = 0; i < 4; ++i) {
    GL2LDS(qbase + goff[i], &sQ[0][ldso[i]]);
    GL2LDS(kbase + goff[i], &sK[0][ldso[i]]);
  }

  for (int h = 0; h < HH; ++h) {
    const int buf = h & 1;
    asm volatile("s_waitcnt vmcnt(0)" ::: "memory");
    __builtin_amdgcn_s_barrier();
    __builtin_amdgcn_sched_barrier(0);

    if (h + 1 < HH) {
      const u16* qn = qbase + (size_t)(h + 1) * TT * HD;
      const u16* kn = kbase + (size_t)(h + 1) * TT * HD;
      const int nb = buf ^ 1;
#pragma unroll
      for (int i = 0; i < 4; ++i) {
        GL2LDS(qn + goff[i], &sQ[nb][ldso[i]]);
        GL2LDS(kn + goff[i], &sK[nb][ldso[i]]);
      }
    }

    float rlv[4];
#pragma unroll
    for (int t = 0; t < 4; ++t)
      rlv[t] = stats_rl[(bhb + h) * TT + q0 + wq + t * 16 + l16];

    bf16x8 qf[4][2];
#pragma unroll
    for (int t = 0; t < 4; ++t) {
      const int row = wq + t * 16 + l16;
#pragma unroll
      for (int ks = 0; ks < 2; ++ks)
        qf[t][ks] = *(const bf16x8*)&sQ[buf][row * 64 + (((ks * 4 + quad) ^ (row & 7)) * 8)];
    }

#pragma unroll
    for (int nt = 0; nt < 4; ++nt) {
      const int krow = ws + nt * 16 + l16;
      bf16x8 kf0 = *(const bf16x8*)&sK[buf][krow * 64 + ((quad ^ (krow & 7)) * 8)];
      bf16x8 kf1 = *(const bf16x8*)&sK[buf][krow * 64 + (((4 + quad) ^ (krow & 7)) * 8)];
#pragma unroll
      for (int tm = 0; tm < 4; ++tm) {
        f32x4 sacc = {};
        sacc = __builtin_amdgcn_mfma_f32_16x16x32_bf16(kf0, qf[tm][0], sacc, 0, 0, 0);
        sacc = __builtin_amdgcn_mfma_f32_16x16x32_bf16(kf1, qf[tm][1], sacc, 0, 0, 0);
#pragma unroll
        for (int r = 0; r < 4; ++r)
          aacc[tm][nt][r] += __expf(sacc[r]) * rlv[tm];
      }
    }
    __builtin_amdgcn_sched_barrier(0);
  }

  const float ih = 1.0f / HH;
#pragma unroll
  for (int tm = 0; tm < 4; ++tm) {
    const int q = q0 + wq + tm * 16 + l16;
    float* orow = avg + ((size_t)b * TT + q) * TT + s0 + ws;
#pragma unroll
    for (int nt = 0; nt < 4; ++nt) {
      float4 o;
      o.x = aacc[tm][nt][0] * ih;
      o.y = aacc[tm][nt][1] * ih;
      o.z = aacc[tm][nt][2] * ih;
      o.w = aacc[tm][nt][3] * ih;
      *(float4*)(orow + nt * 16 + quad * 4) = o;
    }
  }
}

// ---------------------------------------------------------------------------
// K4: output projection — same depth-2 pipeline as K1.
// ---------------------------------------------------------------------------
__global__ __launch_bounds__(256, 3) void proj_out(
    const u16* __restrict__ ctx, const float* __restrict__ ow, const float* __restrict__ ob,
    float* __restrict__ out)
{
  __shared__ u16 sA[2][128 * 40];
  __shared__ u16 sB[2][64 * 40];
  const int tid = threadIdx.x;
  const int w = tid >> 6, lane = tid & 63, l32 = lane & 31, hi = lane >> 5;
  const int wm = w & 1, wn = w >> 1;
  const int bn = blockIdx.x, bm = blockIdx.y;

  const int arow = tid >> 2, acs = tid & 3;
  const u16* ag = ctx + (size_t)(bm * 128 + arow) * EE + acs * 8;
  const int brow = tid >> 3, bcs = tid & 7;
  const float* wg2 = ow + (size_t)(bn * 64 + brow) * EE + bcs * 4;

  f32x16 acc[2] = {};
  uint4 lca[2]; float4 lwb[2];

  // prologue: T0 -> buf0 (direct), then T1 -> regs
#pragma unroll
  for (int i = 0; i < 2; ++i) lca[i] = *(const uint4*)(ag + (size_t)i * 64 * EE);
#pragma unroll
  for (int i = 0; i < 2; ++i) lwb[i] = *(const float4*)(wg2 + (size_t)i * 32 * EE);
#pragma unroll
  for (int i = 0; i < 2; ++i)
    *(uint4*)&sA[0][(i * 64 + arow) * 40 + acs * 8] = lca[i];
#pragma unroll
  for (int i = 0; i < 2; ++i) {
    u64 pk = (u64)cvtpk2(lwb[i].x, lwb[i].y) | ((u64)cvtpk2(lwb[i].z, lwb[i].w) << 32);
    *(u64*)&sB[0][(i * 32 + brow) * 40 + bcs * 4] = pk;
  }
#pragma unroll
  for (int i = 0; i < 2; ++i) lca[i] = *(const uint4*)(ag + (size_t)i * 64 * EE + 32);
#pragma unroll
  for (int i = 0; i < 2; ++i) lwb[i] = *(const float4*)(wg2 + (size_t)i * 32 * EE + 32);

  for (int kt = 0; kt < EE / 32; ++kt) {
    const int buf = kt & 1;
    __syncthreads();
    if (kt + 1 < EE / 32) {
      const int nb = buf ^ 1;
#pragma unroll
      for (int i = 0; i < 2; ++i)
        *(uint4*)&sA[nb][(i * 64 + arow) * 40 + acs * 8] = lca[i];
#pragma unroll
      for (int i = 0; i < 2; ++i) {
        u64 pk = (u64)cvtpk2(lwb[i].x, lwb[i].y) | ((u64)cvtpk2(lwb[i].z, lwb[i].w) << 32);
        *(u64*)&sB[nb][(i * 32 + brow) * 40 + bcs * 4] = pk;
      }
    }
    if (kt + 2 < EE / 32) {
      const int ko = (kt + 2) * 32;
#pragma unroll
      for (int i = 0; i < 2; ++i) lca[i] = *(const uint4*)(ag + (size_t)i * 64 * EE + ko);
#pragma unroll
      for (int i = 0; i < 2; ++i) lwb[i] = *(const float4*)(wg2 + (size_t)i * 32 * EE + ko);
    }
#pragma unroll
    for (int ks = 0; ks < 2; ++ks) {
      bf16x8 bfr = *(const bf16x8*)&sB[buf][(wn * 32 + l32) * 40 + ks * 16 + hi * 8];
#pragma unroll
      for (int tm = 0; tm < 2; ++tm) {
        bf16x8 afr = *(const bf16x8*)&sA[buf][(wm * 64 + tm * 32 + l32) * 40 + ks * 16 + hi * 8];
        acc[tm] = __builtin_amdgcn_mfma_f32_32x32x16_bf16(afr, bfr, acc[tm], 0, 0, 0);
      }
    }
  }

  const int j = bn * 64 + wn * 32 + l32;
  const float bj = ob[j];
#pragma unroll
  for (int tm = 0; tm < 2; ++tm) {
#pragma unroll
    for (int r = 0; r < 16; ++r) {
      int m = bm * 128 + wm * 64 + tm * 32 + (r & 3) + 8 * (r >> 2) + 4 * hi;
      out[(size_t)m * EE + j] = acc[tm][r] + bj;
    }
  }
}

// ---------------------------------------------------------------------------
extern "C" void kernel_launch(void* const* d_in, const int* in_sizes, int n_in,
                              void* d_out, int out_size, void* d_ws, size_t ws_size,
                              hipStream_t stream)
{
  const float* query = (const float*)d_in[0];
  const float* key   = (const float*)d_in[1];
  const float* value = (const float*)d_in[2];
  const float* ipw   = (const float*)d_in[3];
  const float* ipb   = (const float*)d_in[4];
  const float* ow    = (const float*)d_in[5];
  const float* ob    = (const float*)d_in[6];
  float* out = (float*)d_out;

  char* p = (char*)d_ws;
  const size_t QKV = (size_t)BB * HH * TT * HD * 2;  // 12,582,912 B per tensor
  u16* qh  = (u16*)p; p += QKV;
  u16* kh  = (u16*)p; p += QKV;
  u16* vh  = (u16*)p; p += QKV;
  _Float16* vhT = (_Float16*)p; p += QKV;
  u16* ctx = (u16*)p; p += (size_t)NTOK * EE * 2;
  float* stats = (float*)p;

  proj_qkv<<<dim3(768, 1, 1), 256, 0, stream>>>(query, key, value, ipw, ipb, qh, kh, vh);
  transpose_v<<<dim3(32, 48), 256, 0, stream>>>(vh, vhT);
  attn_flash<<<dim3(768, 1, 1), 256, 0, stream>>>(qh, kh, vhT, ctx, stats);
  attn_avg<<<dim3(16, 16, BB), 256, 0, stream>>>(qh, kh, stats, out + (size_t)NTOK * EE);
  proj_out<<<dim3(12, 64), 256, 0, stream>>>(ctx, ow, ob, out);
}

// Round 12
// 358.119 us; speedup vs baseline: 1.0738x; 1.0738x over previous
//
#include <hip/hip_runtime.h>

typedef unsigned short u16;
typedef unsigned long long u64;
typedef __attribute__((ext_vector_type(8))) short bf16x8;
typedef __attribute__((ext_vector_type(4))) float f32x4;
typedef __attribute__((ext_vector_type(16))) float f32x16;
typedef __attribute__((ext_vector_type(4))) _Float16 f16x4;
typedef __attribute__((ext_vector_type(2))) __fp16 h16x2;   // cvt_pkrtz return type

#define TT 2048
#define BB 4
#define EE 768
#define HH 12
#define HD 64
#define NTOK 8192  // TT*BB
#define KVB 32
#define NTILE (TT / KVB)   // 64
// sV row stride in halfs.  MUST keep byte-stride % 8 == 0 (VST=34 regressed
// 74->208us: odd-row f16x4 LDS ops lose 8B alignment -> b64 splits).
#define VST 36

__device__ __forceinline__ u16 f2bf(float f) {
  unsigned int u = __builtin_bit_cast(unsigned int, f);
  u += 0x7fffu + ((u >> 16) & 1u);   // RNE
  return (u16)(u >> 16);
}

__device__ __forceinline__ float bf2f(u16 b) {
  unsigned int u = (unsigned int)b << 16;
  return __builtin_bit_cast(float, u);
}

__device__ __forceinline__ unsigned int pack2(u16 a, u16 b) {
  return (unsigned int)a | ((unsigned int)b << 16);
}

// HW packed fp32->bf16 RNE: lo=cvt(a), hi=cvt(b).  Same rounding as f2bf.
__device__ __forceinline__ unsigned int cvtpk2(float a, float b) {
  unsigned int r;
  asm("v_cvt_pk_bf16_f32 %0, %1, %2" : "=v"(r) : "v"(a), "v"(b));
  return r;
}

__device__ __forceinline__ unsigned int pkh2(float a, float b) {
  h16x2 t = __builtin_amdgcn_cvt_pkrtz(a, b);
  return __builtin_bit_cast(unsigned int, t);
}

// global -> LDS direct copy, 16B per lane (dest = wave-uniform base + lane*16)
#define GL2LDS(gp, lp) __builtin_amdgcn_global_load_lds( \
    (const __attribute__((address_space(1))) void*)(gp), \
    (__attribute__((address_space(3))) void*)(lp), 16, 0, 0)

// ---------------------------------------------------------------------------
// K1: fused QKV projection — depth-2 pipeline KEPT (R11 counters: 100->85us,
// MfmaUtil 11->13%).  ds_write(kt+1) at top of iter kt (regs loaded a full
// iter ago), loads for kt+2 issued after; issue->use distance = 1 iteration.
// ---------------------------------------------------------------------------
__global__ __launch_bounds__(256, 3) void proj_qkv(
    const float* __restrict__ q_in, const float* __restrict__ k_in, const float* __restrict__ v_in,
    const float* __restrict__ ipw, const float* __restrict__ ipb,
    u16* __restrict__ qh, u16* __restrict__ kh, u16* __restrict__ vh)
{
  __shared__ u16 sA[2][128 * 40];
  __shared__ u16 sB[2][192 * 40];
  const int tid = threadIdx.x;
  const int w = tid >> 6, lane = tid & 63, l32 = lane & 31, hi = lane >> 5;
  const int wm = w & 1, wn = w >> 1;
  const int orig = blockIdx.x;
  const int wg = (orig & 7) * 96 + (orig >> 3);
  const int z = wg >> 8;
  const int rem = wg & 255;
  const int bm = rem >> 2, bn = rem & 3;

  const float* A = (z == 0) ? q_in : (z == 1) ? k_in : v_in;
  const float* W = ipw + (size_t)z * EE * EE;
  const float* bias = ipb + z * EE;

  const int srow = tid >> 3, scs = tid & 7;
  const float* ag = A + (size_t)(bm * 128 + srow) * EE + scs * 4;
  const float* wgp = W + (size_t)(bn * 192 + srow) * EE + scs * 4;

  f32x16 acc[2][3] = {};
  float4 la[4], lw[6];

  // prologue: T0 -> buf0 (direct), then T1 -> regs
#pragma unroll
  for (int i = 0; i < 4; ++i) la[i] = *(const float4*)(ag + (size_t)i * 32 * EE);
#pragma unroll
  for (int i = 0; i < 6; ++i) lw[i] = *(const float4*)(wgp + (size_t)i * 32 * EE);
#pragma unroll
  for (int i = 0; i < 4; ++i) {
    u64 pk = (u64)cvtpk2(la[i].x, la[i].y) | ((u64)cvtpk2(la[i].z, la[i].w) << 32);
    *(u64*)&sA[0][(i * 32 + srow) * 40 + scs * 4] = pk;
  }
#pragma unroll
  for (int i = 0; i < 6; ++i) {
    u64 pk = (u64)cvtpk2(lw[i].x, lw[i].y) | ((u64)cvtpk2(lw[i].z, lw[i].w) << 32);
    *(u64*)&sB[0][(i * 32 + srow) * 40 + scs * 4] = pk;
  }
#pragma unroll
  for (int i = 0; i < 4; ++i) la[i] = *(const float4*)(ag + (size_t)i * 32 * EE + 32);
#pragma unroll
  for (int i = 0; i < 6; ++i) lw[i] = *(const float4*)(wgp + (size_t)i * 32 * EE + 32);

  for (int kt = 0; kt < EE / 32; ++kt) {
    const int buf = kt & 1;
    __syncthreads();   // buf's writes (prev iter) visible; buf^1 free to write
    if (kt + 1 < EE / 32) {
      const int nb = buf ^ 1;
      // T(kt+1): regs (loads issued one full iteration ago) -> LDS
#pragma unroll
      for (int i = 0; i < 4; ++i) {
        u64 pk = (u64)cvtpk2(la[i].x, la[i].y) | ((u64)cvtpk2(la[i].z, la[i].w) << 32);
        *(u64*)&sA[nb][(i * 32 + srow) * 40 + scs * 4] = pk;
      }
#pragma unroll
      for (int i = 0; i < 6; ++i) {
        u64 pk = (u64)cvtpk2(lw[i].x, lw[i].y) | ((u64)cvtpk2(lw[i].z, lw[i].w) << 32);
        *(u64*)&sB[nb][(i * 32 + srow) * 40 + scs * 4] = pk;
      }
    }
    if (kt + 2 < EE / 32) {
      const int ko = (kt + 2) * 32;
#pragma unroll
      for (int i = 0; i < 4; ++i) la[i] = *(const float4*)(ag + (size_t)i * 32 * EE + ko);
#pragma unroll
      for (int i = 0; i < 6; ++i) lw[i] = *(const float4*)(wgp + (size_t)i * 32 * EE + ko);
    }
#pragma unroll
    for (int ks = 0; ks < 2; ++ks) {
      bf16x8 bfr[3];
#pragma unroll
      for (int tn = 0; tn < 3; ++tn)
        bfr[tn] = *(const bf16x8*)&sB[buf][(wn * 96 + tn * 32 + l32) * 40 + ks * 16 + hi * 8];
#pragma unroll
      for (int tm = 0; tm < 2; ++tm) {
        bf16x8 afr = *(const bf16x8*)&sA[buf][(wm * 64 + tm * 32 + l32) * 40 + ks * 16 + hi * 8];
#pragma unroll
        for (int tn = 0; tn < 3; ++tn)
          acc[tm][tn] = __builtin_amdgcn_mfma_f32_32x32x16_bf16(afr, bfr[tn], acc[tm][tn], 0, 0, 0);
      }
    }
  }

  const float scale = (z == 0) ? 0.125f : 1.0f;
  u16* dst = (z == 0) ? qh : (z == 1) ? kh : vh;
#pragma unroll
  for (int tn = 0; tn < 3; ++tn) {
    const int j = bn * 192 + wn * 96 + tn * 32 + l32;
    const int h = j >> 6, d = j & 63;
    const float bj = bias[j];
#pragma unroll
    for (int tm = 0; tm < 2; ++tm) {
#pragma unroll
      for (int r = 0; r < 16; ++r) {
        int m = bm * 128 + wm * 64 + tm * 32 + (r & 3) + 8 * (r >> 2) + 4 * hi;
        int t = m >> 2, bb = m & 3;
        float v = (acc[tm][tn][r] + bj) * scale;
        dst[((size_t)((bb * HH + h) * TT + t)) * HD + d] = f2bf(v);
      }
    }
  }
}

// ---------------------------------------------------------------------------
// K1b: transpose V per head:  vh bf16 [bh][t][d]  ->  vhT f16 [bh][d][t]
// ---------------------------------------------------------------------------
__global__ __launch_bounds__(256) void transpose_v(
    const u16* __restrict__ vh, _Float16* __restrict__ vhT)
{
  __shared__ u16 tile[64][72];
  const int tid = threadIdx.x;
  const int bh = blockIdx.y;
  const int t0 = blockIdx.x * 64;
  {
    int row = tid >> 2, seg = tid & 3;
    const u16* src = vh + (size_t)bh * TT * HD + (size_t)(t0 + row) * HD + seg * 16;
    uint4 a = *(const uint4*)(src);
    uint4 b = *(const uint4*)(src + 8);
    *(uint4*)&tile[row][seg * 16] = a;
    *(uint4*)&tile[row][seg * 16 + 8] = b;
  }
  __syncthreads();
  {
    int d = tid >> 2, ts = tid & 3;
    u16 tmp[16];
#pragma unroll
    for (int i = 0; i < 16; ++i) tmp[i] = tile[ts * 16 + i][d];
    unsigned int pk[8];
#pragma unroll
    for (int i = 0; i < 8; ++i)
      pk[i] = pkh2(bf2f(tmp[2 * i]), bf2f(tmp[2 * i + 1]));
    uint4 o0, o1;
    o0.x = pk[0]; o0.y = pk[1]; o0.z = pk[2]; o0.w = pk[3];
    o1.x = pk[4]; o1.y = pk[5]; o1.z = pk[6]; o1.w = pk[7];
    _Float16* dst = vhT + (size_t)bh * HD * TT + (size_t)d * TT + t0 + ts * 16;
    *(uint4*)dst = o0;
    *(uint4*)(dst + 8) = o1;
  }
}

// ---------------------------------------------------------------------------
// K2: attention — byte-exact R6 structure (proven 74us), VST=36.
// ---------------------------------------------------------------------------
__global__ __launch_bounds__(256, 3) void attn_flash(
    const u16* __restrict__ qh, const u16* __restrict__ kh, const _Float16* __restrict__ vhT,
    u16* __restrict__ ctx, float* __restrict__ stats_rl)
{
  __shared__ u16 sK[2][KVB * 64];          // [buf][row*64 + swz-chunk], 128B rows
  __shared__ _Float16 sV[2][64 * VST];     // [buf][d*VST + s], 72B rows

  const int tid = threadIdx.x, w = tid >> 6, lane = tid & 63;
  const int l16 = lane & 15, quad = lane >> 4;
  const int orig = blockIdx.x;
  const int wg = (orig & 7) * 96 + (orig >> 3);
  const int qb = wg & 15;          // 16 q-blocks of 128
  const int bhl = wg >> 4;         // 0..47
  const int b = bhl / HH, h = bhl - b * HH;
  const int q0 = qb * 128 + w * 32;
  const size_t bh = (size_t)bhl;
  const u16* qg = qh + (bh * TT + q0) * HD;
  const u16* kg = kh + bh * TT * HD;
  const _Float16* vg = vhT + bh * HD * TT;

  const int krow = tid >> 3, kch = tid & 7;            // K: 32 rows x 8 x 16B
  const int kdst = krow * 64 + ((kch ^ (krow & 7)) * 8);
  const u16* kgp = kg + (size_t)krow * HD + kch * 8;
  const int vrow = tid >> 2, vch = tid & 3;            // V: 64 rows x 4 x 16B
  const int vdst = vrow * VST + vch * 8;
  const _Float16* vgp = vg + (size_t)vrow * TT + vch * 8;

  bf16x8 qf[2][2];
#pragma unroll
  for (int j = 0; j < 2; ++j)
#pragma unroll
    for (int p = 0; p < 2; ++p)
      qf[j][p] = *(const bf16x8*)(qg + (j * 16 + l16) * HD + p * 32 + quad * 8);

  f32x4 oacc[2][4] = {};
  float lsum[2] = {0.0f, 0.0f};

  {
    uint4 kv = *(const uint4*)kgp;
    uint4 vv = *(const uint4*)vgp;
    *(uint4*)&sK[0][kdst] = kv;
    *(u64*)&sV[0][vdst]     = ((const u64*)&vv)[0];
    *(u64*)&sV[0][vdst + 4] = ((const u64*)&vv)[1];
  }

  for (int st = 0; st < NTILE; ++st) {
    const int buf = st & 1;
    uint4 nk, nv;
    const bool more = (st + 1 < NTILE);
    if (more) {        // issue before the barrier (R6-proven placement)
      nk = *(const uint4*)(kgp + (size_t)(st + 1) * KVB * HD);
      nv = *(const uint4*)(vgp + (st + 1) * KVB);
    }
    __syncthreads();

    const u16* kb = &sK[buf][0];
    const _Float16* vb = &sV[buf][0];
#pragma unroll
    for (int ss = 0; ss < 2; ++ss) {
      const int krw = ss * 16 + l16;
      bf16x8 kf0 = *(const bf16x8*)&kb[krw * 64 + ((quad ^ (krw & 7)) * 8)];
      bf16x8 kf1 = *(const bf16x8*)&kb[krw * 64 + (((4 + quad) ^ (krw & 7)) * 8)];
      f16x4 vf[4];
#pragma unroll
      for (int m = 0; m < 4; ++m)
        vf[m] = *(const f16x4*)&vb[(m * 16 + l16) * VST + ss * 16 + quad * 4];
#pragma unroll
      for (int j = 0; j < 2; ++j) {
        f32x4 z = {};
        f32x4 T = __builtin_amdgcn_mfma_f32_16x16x32_bf16(kf0, qf[j][0], z, 0, 0, 0);
        T = __builtin_amdgcn_mfma_f32_16x16x32_bf16(kf1, qf[j][1], T, 0, 0, 0);
        float p0 = __expf(T[0]), p1 = __expf(T[1]), p2 = __expf(T[2]), p3 = __expf(T[3]);
        lsum[j] += (p0 + p1) + (p2 + p3);
        uint2 uu;
        uu.x = pkh2(p0, p1);
        uu.y = pkh2(p2, p3);
        f16x4 pb = __builtin_bit_cast(f16x4, uu);
#pragma unroll
        for (int m = 0; m < 4; ++m)
          oacc[j][m] = __builtin_amdgcn_mfma_f32_16x16x16f16(vf[m], pb, oacc[j][m], 0, 0, 0);
      }
    }

    if (more) {
      const int nb = buf ^ 1;
      *(uint4*)&sK[nb][kdst] = nk;
      *(u64*)&sV[nb][vdst]     = ((const u64*)&nv)[0];
      *(u64*)&sV[nb][vdst + 4] = ((const u64*)&nv)[1];
    }
  }

#pragma unroll
  for (int j = 0; j < 2; ++j) {
    float s = lsum[j];
    s += __shfl_xor(s, 16);
    s += __shfl_xor(s, 32);
    float rl = 1.0f / s;
    const int q = q0 + j * 16 + l16;
    if (quad == 0) stats_rl[bh * TT + q] = rl;
    u16* crow = ctx + (size_t)(q * BB + b) * EE + h * HD;
#pragma unroll
    for (int m = 0; m < 4; ++m) {
      u64 pk =
          (u64)pack2(f2bf(oacc[j][m][0] * rl), f2bf(oacc[j][m][1] * rl)) |
          ((u64)pack2(f2bf(oacc[j][m][2] * rl), f2bf(oacc[j][m][3] * rl)) << 32);
      *(u64*)(crow + m * 16 + quad * 4) = pk;
    }
  }
}

// ---------------------------------------------------------------------------
// K3: avg_weights (unchanged from round 6 — gload_lds dbuf, raw barrier,
// launch_bounds(256,2)).
// ---------------------------------------------------------------------------
__global__ __launch_bounds__(256, 2) void attn_avg(
    const u16* __restrict__ qh, const u16* __restrict__ kh,
    const float* __restrict__ stats_rl, float* __restrict__ avg)
{
  __shared__ u16 sQ[2][128 * 64];
  __shared__ u16 sK[2][128 * 64];
  const int tid = threadIdx.x, w = tid >> 6, lane = tid & 63;
  const int l16 = lane & 15, quad = lane >> 4;
  const int b = blockIdx.z;
  const int q0 = blockIdx.y * 128, s0 = blockIdx.x * 128;
  const int wq = (w & 1) * 64, ws = (w >> 1) * 64;

  int goff[4], ldso[4];
#pragma unroll
  for (int i = 0; i < 4; ++i) {
    const int g = i * 256 + tid;
    const int row = g >> 3, c = g & 7;
    goff[i] = row * HD + ((c ^ (row & 7)) * 8);        // u16 units
    ldso[i] = (i * 256 + (tid & ~63)) * 8;             // wave-uniform, u16 units
  }
  const size_t bhb = (size_t)b * HH;
  const u16* qbase = qh + (bhb * TT + q0) * HD;
  const u16* kbase = kh + (bhb * TT + s0) * HD;

  f32x4 aacc[4][4] = {};

#pragma unroll
  for (int i = 0; i < 4; ++i) {
    GL2LDS(qbase + goff[i], &sQ[0][ldso[i]]);
    GL2LDS(kbase + goff[i], &sK[0][ldso[i]]);
  }

  for (int h = 0; h < HH; ++h) {
    const int buf = h & 1;
    asm volatile("s_waitcnt vmcnt(0)" ::: "memory");
    __builtin_amdgcn_s_barrier();
    __builtin_amdgcn_sched_barrier(0);

    if (h + 1 < HH) {
      const u16* qn = qbase + (size_t)(h + 1) * TT * HD;
      const u16* kn = kbase + (size_t)(h + 1) * TT * HD;
      const int nb = buf ^ 1;
#pragma unroll
      for (int i = 0; i < 4; ++i) {
        GL2LDS(qn + goff[i], &sQ[nb][ldso[i]]);
        GL2LDS(kn + goff[i], &sK[nb][ldso[i]]);
      }
    }

    float rlv[4];
#pragma unroll
    for (int t = 0; t < 4; ++t)
      rlv[t] = stats_rl[(bhb + h) * TT + q0 + wq + t * 16 + l16];

    bf16x8 qf[4][2];
#pragma unroll
    for (int t = 0; t < 4; ++t) {
      const int row = wq + t * 16 + l16;
#pragma unroll
      for (int ks = 0; ks < 2; ++ks)
        qf[t][ks] = *(const bf16x8*)&sQ[buf][row * 64 + (((ks * 4 + quad) ^ (row & 7)) * 8)];
    }

#pragma unroll
    for (int nt = 0; nt < 4; ++nt) {
      const int krow = ws + nt * 16 + l16;
      bf16x8 kf0 = *(const bf16x8*)&sK[buf][krow * 64 + ((quad ^ (krow & 7)) * 8)];
      bf16x8 kf1 = *(const bf16x8*)&sK[buf][krow * 64 + (((4 + quad) ^ (krow & 7)) * 8)];
#pragma unroll
      for (int tm = 0; tm < 4; ++tm) {
        f32x4 sacc = {};
        sacc = __builtin_amdgcn_mfma_f32_16x16x32_bf16(kf0, qf[tm][0], sacc, 0, 0, 0);
        sacc = __builtin_amdgcn_mfma_f32_16x16x32_bf16(kf1, qf[tm][1], sacc, 0, 0, 0);
#pragma unroll
        for (int r = 0; r < 4; ++r)
          aacc[tm][nt][r] += __expf(sacc[r]) * rlv[tm];
      }
    }
    __builtin_amdgcn_sched_barrier(0);
  }

  const float ih = 1.0f / HH;
#pragma unroll
  for (int tm = 0; tm < 4; ++tm) {
    const int q = q0 + wq + tm * 16 + l16;
    float* orow = avg + ((size_t)b * TT + q) * TT + s0 + ws;
#pragma unroll
    for (int nt = 0; nt < 4; ++nt) {
      float4 o;
      o.x = aacc[tm][nt][0] * ih;
      o.y = aacc[tm][nt][1] * ih;
      o.z = aacc[tm][nt][2] * ih;
      o.w = aacc[tm][nt][3] * ih;
      *(float4*)(orow + nt * 16 + quad * 4) = o;
    }
  }
}

// ---------------------------------------------------------------------------
// K4: output projection — REVERTED to R10 structure (prefetch after barrier,
// ds_write at end).  R11's depth-2 regressed the total +38us: proj_out's
// iteration is too thin (4 MFMAs) to absorb the top-of-loop ds_write block.
// ---------------------------------------------------------------------------
__global__ __launch_bounds__(256, 3) void proj_out(
    const u16* __restrict__ ctx, const float* __restrict__ ow, const float* __restrict__ ob,
    float* __restrict__ out)
{
  __shared__ u16 sA[2][128 * 40];
  __shared__ u16 sB[2][64 * 40];
  const int tid = threadIdx.x;
  const int w = tid >> 6, lane = tid & 63, l32 = lane & 31, hi = lane >> 5;
  const int wm = w & 1, wn = w >> 1;
  const int bn = blockIdx.x, bm = blockIdx.y;

  const int arow = tid >> 2, acs = tid & 3;
  const u16* ag = ctx + (size_t)(bm * 128 + arow) * EE + acs * 8;
  const int brow = tid >> 3, bcs = tid & 7;
  const float* wg2 = ow + (size_t)(bn * 64 + brow) * EE + bcs * 4;

  f32x16 acc[2] = {};
  uint4 lca[2]; float4 lwb[2];

#pragma unroll
  for (int i = 0; i < 2; ++i) lca[i] = *(const uint4*)(ag + (size_t)i * 64 * EE);
#pragma unroll
  for (int i = 0; i < 2; ++i) lwb[i] = *(const float4*)(wg2 + (size_t)i * 32 * EE);
#pragma unroll
  for (int i = 0; i < 2; ++i)
    *(uint4*)&sA[0][(i * 64 + arow) * 40 + acs * 8] = lca[i];
#pragma unroll
  for (int i = 0; i < 2; ++i) {
    u64 pk = (u64)cvtpk2(lwb[i].x, lwb[i].y) | ((u64)cvtpk2(lwb[i].z, lwb[i].w) << 32);
    *(u64*)&sB[0][(i * 32 + brow) * 40 + bcs * 4] = pk;
  }

  for (int kt = 0; kt < EE / 32; ++kt) {
    const int buf = kt & 1;
    const bool more = (kt + 1) < EE / 32;
    __syncthreads();
    if (more) {
      const int ko = (kt + 1) * 32;
#pragma unroll
      for (int i = 0; i < 2; ++i) lca[i] = *(const uint4*)(ag + (size_t)i * 64 * EE + ko);
#pragma unroll
      for (int i = 0; i < 2; ++i) lwb[i] = *(const float4*)(wg2 + (size_t)i * 32 * EE + ko);
    }
#pragma unroll
    for (int ks = 0; ks < 2; ++ks) {
      bf16x8 bfr = *(const bf16x8*)&sB[buf][(wn * 32 + l32) * 40 + ks * 16 + hi * 8];
#pragma unroll
      for (int tm = 0; tm < 2; ++tm) {
        bf16x8 afr = *(const bf16x8*)&sA[buf][(wm * 64 + tm * 32 + l32) * 40 + ks * 16 + hi * 8];
        acc[tm] = __builtin_amdgcn_mfma_f32_32x32x16_bf16(afr, bfr, acc[tm], 0, 0, 0);
      }
    }
    if (more) {
      const int nb = buf ^ 1;
#pragma unroll
      for (int i = 0; i < 2; ++i)
        *(uint4*)&sA[nb][(i * 64 + arow) * 40 + acs * 8] = lca[i];
#pragma unroll
      for (int i = 0; i < 2; ++i) {
        u64 pk = (u64)cvtpk2(lwb[i].x, lwb[i].y) | ((u64)cvtpk2(lwb[i].z, lwb[i].w) << 32);
        *(u64*)&sB[nb][(i * 32 + brow) * 40 + bcs * 4] = pk;
      }
    }
  }

  const int j = bn * 64 + wn * 32 + l32;
  const float bj = ob[j];
#pragma unroll
  for (int tm = 0; tm < 2; ++tm) {
#pragma unroll
    for (int r = 0; r < 16; ++r) {
      int m = bm * 128 + wm * 64 + tm * 32 + (r & 3) + 8 * (r >> 2) + 4 * hi;
      out[(size_t)m * EE + j] = acc[tm][r] + bj;
    }
  }
}

// ---------------------------------------------------------------------------
extern "C" void kernel_launch(void* const* d_in, const int* in_sizes, int n_in,
                              void* d_out, int out_size, void* d_ws, size_t ws_size,
                              hipStream_t stream)
{
  const float* query = (const float*)d_in[0];
  const float* key   = (const float*)d_in[1];
  const float* value = (const float*)d_in[2];
  const float* ipw   = (const float*)d_in[3];
  const float* ipb   = (const float*)d_in[4];
  const float* ow    = (const float*)d_in[5];
  const float* ob    = (const float*)d_in[6];
  float* out = (float*)d_out;

  char* p = (char*)d_ws;
  const size_t QKV = (size_t)BB * HH * TT * HD * 2;  // 12,582,912 B per tensor
  u16* qh  = (u16*)p; p += QKV;
  u16* kh  = (u16*)p; p += QKV;
  u16* vh  = (u16*)p; p += QKV;
  _Float16* vhT = (_Float16*)p; p += QKV;
  u16* ctx = (u16*)p; p += (size_t)NTOK * EE * 2;
  float* stats = (float*)p;

  proj_qkv<<<dim3(768, 1, 1), 256, 0, stream>>>(query, key, value, ipw, ipb, qh, kh, vh);
  transpose_v<<<dim3(32, 48), 256, 0, stream>>>(vh, vhT);
  attn_flash<<<dim3(768, 1, 1), 256, 0, stream>>>(qh, kh, vhT, ctx, stats);
  attn_avg<<<dim3(16, 16, BB), 256, 0, stream>>>(qh, kh, stats, out + (size_t)NTOK * EE);
  proj_out<<<dim3(12, 64), 256, 0, stream>>>(ctx, ow, ob, out);
}